// Round 7
// baseline (7231.850 us; speedup 1.0000x reference)
//
#include <hip/hip_runtime.h>
#include <hip/hip_bf16.h>

typedef __bf16 bf16_t;
typedef __bf16 bf16x8 __attribute__((ext_vector_type(8)));
typedef float f32x4 __attribute__((ext_vector_type(4)));
typedef int i32x4 __attribute__((ext_vector_type(4)));

#define HDIM 256
#define TSTEPS 64
#define DIN 64
#define BM 64
#define NBLK 256  // 16384 / 64

__device__ __forceinline__ float fast_tanh(float x) {
    float e = __builtin_amdgcn_exp2f(x * 2.8853900817779268f);
    return 1.0f - 2.0f * __builtin_amdgcn_rcpf(e + 1.0f);
}
__device__ __forceinline__ float fast_sigmoid(float x) {
    float e = __builtin_amdgcn_exp2f(-x * 1.4426950408889634f);
    return __builtin_amdgcn_rcpf(1.0f + e);
}

// swizzled LDS byte address for h tiles: row-major [64][256] bf16 (stride 512B)
__device__ __forceinline__ unsigned lds_addr(int row, int kb) {
    return (unsigned)(row * 512 + (kb ^ ((row & 7) << 4)));
}
// swizzled LDS byte address for x tile: row-major [64][64] bf16 (stride 128B)
__device__ __forceinline__ unsigned lx_addr(int row, int kb) {
    return (unsigned)(row * 128 + (kb ^ ((row & 7) << 4)));
}

// volatile LDS helpers: volatile ops keep program order vs each other and vs
// asm volatile / s_barrier — this is what makes the raw-barrier protocol safe
// at IR level (round-5 race: non-volatile LDS reads hoisted above s_barrier,
// which is IntrNoMem). No extra waitcnts are generated: global weight loads
// stay in flight across BAR().
__device__ __forceinline__ bf16x8 lds_ld8(const char* p) {
    return *(const volatile bf16x8*)p;
}
__device__ __forceinline__ void lds_st1(char* p, bf16_t v) {
    *(volatile bf16_t*)p = v;
}

// raw barrier: waits LDS ops only — does NOT drain vmcnt.
#define BAR()                                      \
    do {                                           \
        __builtin_amdgcn_sched_barrier(0);         \
        asm volatile("s_waitcnt lgkmcnt(0)");      \
        __builtin_amdgcn_s_barrier();              \
        __builtin_amdgcn_sched_barrier(0);         \
    } while (0)

// ---------------- weight packing (prologue) ----------------
// Chunk layout (kc-major, n2-minor):
//   chunk = (wave*KC + kc)*2 + n2, element ((chunk)*64 + lane)*8 + i holds
//   W[n = (wave*2+n2)*16 + (lane&15)][k = kc*32 + (lane>>4)*8 + i]
__global__ void pack_w(const float* __restrict__ s0, const float* __restrict__ s1,
                       int ksplit, int stride0, int stride1, int off0, int off1,
                       int KC, bf16_t* __restrict__ dst) {
    int idx = blockIdx.x * 256 + threadIdx.x;
    int total = 256 * KC * 32;
    if (idx >= total) return;
    int i = idx & 7;
    int lane = (idx >> 3) & 63;
    int chunk = idx >> 9;
    int n2 = chunk & 1;
    int rest = chunk >> 1;
    int kc = rest % KC, wv = rest / KC;
    int nt = wv * 2 + n2;
    int n = nt * 16 + (lane & 15);
    int k = kc * 32 + ((lane >> 4) * 8) + i;
    float v = (k < ksplit) ? s0[n * stride0 + off0 + k]
                           : s1[n * stride1 + off1 + (k - ksplit)];
    dst[idx] = (bf16_t)v;
}

__global__ void pack_bias(const float* __restrict__ b_ih1, const float* __restrict__ b_hh1,
                          const float* __restrict__ b_ih2, const float* __restrict__ b_hh2,
                          const float* __restrict__ b_g,
                          float* __restrict__ bias1, float* __restrict__ bias2a,
                          float* __restrict__ biasg) {
    int j = threadIdx.x;
    bias1[j] = b_ih1[j] + b_hh1[j];
    bias2a[j] = b_ih2[j] + b_hh2[j];
    biasg[j] = b_g[j];
}

#define ISSUE(BUF, PB, N)                                            \
    _Pragma("unroll") for (int c = 0; c < (N); ++c)                  \
        BUF[c] = *(const bf16x8*)((PB) + c * 512 + (lane << 3));

#define GEMM_PH(NKK, BUF, ASRC, KC0, ACC)                                             \
    _Pragma("unroll") for (int kk = 0; kk < (NKK); ++kk) {                            \
        bf16x8 a_[4];                                                                 \
        _Pragma("unroll") for (int mt = 0; mt < 4; ++mt)                              \
            a_[mt] = lds_ld8((ASRC) + lds_addr(mt * 16 + l15,                         \
                                               ((KC0) + kk) * 64 + l4 * 16));         \
        _Pragma("unroll") for (int mt = 0; mt < 4; ++mt) {                            \
            ACC[mt][0] = __builtin_amdgcn_mfma_f32_16x16x32_bf16(a_[mt], BUF[kk * 2 + 0], ACC[mt][0], 0, 0, 0); \
            ACC[mt][1] = __builtin_amdgcn_mfma_f32_16x16x32_bf16(a_[mt], BUF[kk * 2 + 1], ACC[mt][1], 0, 0, 0); \
        }                                                                             \
    }

// ---------------- main persistent RNN kernel ----------------
__global__ __launch_bounds__(512, 1) void rnn_main(
    const float* __restrict__ x,
    const bf16_t* __restrict__ pw_ih1,   // N=256 K=64  (KC=2)
    const bf16_t* __restrict__ pw_hh1,   // N=256 K=256 (KC=8)
    const bf16_t* __restrict__ pw_2a,    // N=256 K=512 (KC=16): k<256 W_ih2, k>=256 W_hh2
    const bf16_t* __restrict__ pw_2b,    // N=256 K=256 (KC=8): Wg[:, 0:256]
    const bf16_t* __restrict__ pw_3,     // N=256 K=256 (KC=8): Wg[:, 256:512]
    const float* __restrict__ bias1v, const float* __restrict__ bias2av,
    const float* __restrict__ biasgv,
    const float* __restrict__ wo1, const float* __restrict__ bo1p,
    const float* __restrict__ wo2, const float* __restrict__ bo2p,
    float* __restrict__ out) {
    __shared__ char lds[90112];
    char* lh1 = lds;            // [64][256] bf16 swizzled
    char* lh2 = lds + 32768;    // [64][256] bf16 swizzled
    char* lx  = lds + 65536;    // [64][64]  bf16 swizzled (x tile)
    volatile float* lout = (volatile float*)(lds + 73728);  // [64][64] f32 linear

    const int tid = threadIdx.x;
    const int wave = tid >> 6, lane = tid & 63;
    const int l15 = lane & 15, l4 = lane >> 4;
    const int b0 = blockIdx.x * BM;

    {   // zero h1, h2 in LDS (initial state) — volatile so it can't sink past BAR
        i32x4 z = {0, 0, 0, 0};
        for (int i = tid; i < 4096; i += 512) ((volatile i32x4*)lds)[i] = z;
    }

    f32x4 u_reg[4][2];
#pragma unroll
    for (int mt = 0; mt < 4; ++mt)
#pragma unroll
        for (int n2 = 0; n2 < 2; ++n2) u_reg[mt][n2] = (f32x4){1.f, 1.f, 1.f, 1.f};

    float bias1_r[2], bias2a_r[2], biasg_r[2];
#pragma unroll
    for (int n2 = 0; n2 < 2; ++n2) {
        int col = wave * 32 + n2 * 16 + l15;
        bias1_r[n2] = bias1v[col];
        bias2a_r[n2] = bias2av[col];
        biasg_r[n2] = biasgv[col];
    }
    const float bo1 = bo1p[0], bo2 = bo2p[0];
    const int orow = tid >> 3, oseg = tid & 7;
    const int xrow = tid >> 3, xc16 = (tid & 7) * 16;
    const float* xbase = x + (size_t)(b0 + xrow) * (TSTEPS * DIN) + (tid & 7) * 8;

    // per-wave contiguous stream bases (element offsets)
    const bf16_t* base_ih1 = pw_ih1 + wave * 2048;    // 4 chunks
    const bf16_t* base_hh1 = pw_hh1 + wave * 8192;    // 16 chunks
    const bf16_t* base_2a  = pw_2a  + wave * 16384;   // 32 chunks
    const bf16_t* base_2b  = pw_2b  + wave * 8192;    // 16 chunks
    const bf16_t* base_3   = pw_3   + wave * 8192;    // 16 chunks

    // ring-3 weight buffers; 12 groups/step, consume g then issue g+3
    bf16x8 R0[8], R1[8], R2[8];

    // prologue: stage x(t=0) into lx; warm the ring (g0,g1,g2)
    {
        f32x4 xv0 = __builtin_nontemporal_load((const f32x4*)xbase);
        f32x4 xv1 = __builtin_nontemporal_load((const f32x4*)(xbase + 4));
        bf16x8 xa;
        xa[0] = (bf16_t)xv0[0]; xa[1] = (bf16_t)xv0[1]; xa[2] = (bf16_t)xv0[2]; xa[3] = (bf16_t)xv0[3];
        xa[4] = (bf16_t)xv1[0]; xa[5] = (bf16_t)xv1[1]; xa[6] = (bf16_t)xv1[2]; xa[7] = (bf16_t)xv1[3];
        *(volatile bf16x8*)(lx + lx_addr(xrow, xc16)) = xa;
    }
    ISSUE(R0, base_ih1, 4);            // g0
    ISSUE(R1, base_hh1, 8);            // g1
    ISSUE(R2, base_hh1 + 4096, 8);     // g2
    BAR();

    for (int t = 0; t < TSTEPS; ++t) {
        // ---- P0: consume R0=g0 (x-GEMM, A from lx) | issue g3 ----
        f32x4 acc[4][2];
#pragma unroll
        for (int mt = 0; mt < 4; ++mt)
#pragma unroll
            for (int n2 = 0; n2 < 2; ++n2) acc[mt][n2] = (f32x4){0.f, 0.f, 0.f, 0.f};
#pragma unroll
        for (int kk = 0; kk < 2; ++kk) {
            bf16x8 a_[4];
#pragma unroll
            for (int mt = 0; mt < 4; ++mt)
                a_[mt] = lds_ld8(lx + lx_addr(mt * 16 + l15, kk * 64 + l4 * 16));
#pragma unroll
            for (int mt = 0; mt < 4; ++mt) {
                acc[mt][0] = __builtin_amdgcn_mfma_f32_16x16x32_bf16(a_[mt], R0[kk * 2 + 0], acc[mt][0], 0, 0, 0);
                acc[mt][1] = __builtin_amdgcn_mfma_f32_16x16x32_bf16(a_[mt], R0[kk * 2 + 1], acc[mt][1], 0, 0, 0);
            }
        }
        ISSUE(R0, base_2a, 8);                 // g3
        // issue x(t+1) global loads (consumed after the lh2 window)
        f32x4 xv0, xv1;
        {
            int tn = t + 1; if (tn > TSTEPS - 1) tn = TSTEPS - 1;
            const float* xp = xbase + tn * DIN;
            xv0 = __builtin_nontemporal_load((const f32x4*)xp);
            xv1 = __builtin_nontemporal_load((const f32x4*)(xp + 4));
        }
        // ---- P1: consume R1=g1 (hh1 kc0-3) | issue g4 ----
        GEMM_PH(4, R1, lh1, 0, acc)
        ISSUE(R1, base_2a + 4096, 8);          // g4
        // ---- P2: consume R2=g2 (hh1 kc4-7) | issue g5 ----
        GEMM_PH(4, R2, lh1, 4, acc)
        ISSUE(R2, base_2a + 8192, 8);          // g5

        // ---- h1 epilogue ----
        float h1n[4][2][4];
#pragma unroll
        for (int mt = 0; mt < 4; ++mt)
#pragma unroll
            for (int n2 = 0; n2 < 2; ++n2)
#pragma unroll
                for (int r = 0; r < 4; ++r)
                    h1n[mt][n2][r] = fast_tanh(acc[mt][n2][r] + bias1_r[n2]);
        BAR();  // all waves done reading old lh1 / lx / prev out-proj
#pragma unroll
        for (int mt = 0; mt < 4; ++mt)
#pragma unroll
            for (int n2 = 0; n2 < 2; ++n2)
#pragma unroll
                for (int r = 0; r < 4; ++r)
                    lds_st1(lh1 + lds_addr(mt * 16 + l4 * 4 + r,
                                           (wave * 32 + n2 * 16 + l15) * 2), (bf16_t)h1n[mt][n2][r]);
        BAR();  // h1new visible

        // ---- P3..P6: GEMM2a (K=512: lh1new kc0-7, lh2old kc0-7) ----
        f32x4 accz[4][2];
#pragma unroll
        for (int mt = 0; mt < 4; ++mt)
#pragma unroll
            for (int n2 = 0; n2 < 2; ++n2) accz[mt][n2] = (f32x4){0.f, 0.f, 0.f, 0.f};
        GEMM_PH(4, R0, lh1, 0, accz)           // P3: g3
        ISSUE(R0, base_2a + 12288, 8);         // g6
        GEMM_PH(4, R1, lh1, 4, accz)           // P4: g4
        ISSUE(R1, base_2b, 8);                 // g7
        GEMM_PH(4, R2, lh2, 0, accz)           // P5: g5 (h2 old)
        ISSUE(R2, base_2b + 4096, 8);          // g8
        GEMM_PH(4, R0, lh2, 4, accz)           // P6: g6 (h2 old)
        ISSUE(R0, base_3, 8);                  // g9

        // ---- blend: z2 = tanh(accz+b); h2n = u*z2 + (1-u)*h2old (h2old from LDS) ----
        float h2n[4][2][4];
#pragma unroll
        for (int mt = 0; mt < 4; ++mt)
#pragma unroll
            for (int n2 = 0; n2 < 2; ++n2)
#pragma unroll
                for (int r = 0; r < 4; ++r) {
                    float z2 = fast_tanh(accz[mt][n2][r] + bias2a_r[n2]);
                    float h2o = (float)*(const volatile bf16_t*)(lh2 + lds_addr(mt * 16 + l4 * 4 + r,
                                                                                (wave * 32 + n2 * 16 + l15) * 2));
                    float un = u_reg[mt][n2][r];
                    h2n[mt][n2][r] = un * z2 + (1.f - un) * h2o;
                }
        BAR();  // all waves done reading old lh2 (and lx from P0)
        // write h2new to lh2, x(t+1) to lx (visible after next BAR)
#pragma unroll
        for (int mt = 0; mt < 4; ++mt)
#pragma unroll
            for (int n2 = 0; n2 < 2; ++n2)
#pragma unroll
                for (int r = 0; r < 4; ++r)
                    lds_st1(lh2 + lds_addr(mt * 16 + l4 * 4 + r,
                                           (wave * 32 + n2 * 16 + l15) * 2), (bf16_t)h2n[mt][n2][r]);
        {
            bf16x8 xa;
            xa[0] = (bf16_t)xv0[0]; xa[1] = (bf16_t)xv0[1]; xa[2] = (bf16_t)xv0[2]; xa[3] = (bf16_t)xv0[3];
            xa[4] = (bf16_t)xv1[0]; xa[5] = (bf16_t)xv1[1]; xa[6] = (bf16_t)xv1[2]; xa[7] = (bf16_t)xv1[3];
            *(volatile bf16x8*)(lx + lx_addr(xrow, xc16)) = xa;
        }

        // ---- P7 (inside write window, reads lh1 only): consume g7 | issue g10 ----
        f32x4 accg[4][2];
#pragma unroll
        for (int mt = 0; mt < 4; ++mt)
#pragma unroll
            for (int n2 = 0; n2 < 2; ++n2) accg[mt][n2] = (f32x4){0.f, 0.f, 0.f, 0.f};
        GEMM_PH(4, R1, lh1, 0, accg)           // g7
        ISSUE(R1, base_3 + 4096, 4);           // g10
        BAR();  // h2new + x(t+1) visible

        // ---- P8..P11 ----
        GEMM_PH(4, R2, lh1, 4, accg)           // P8: g8
        ISSUE(R2, base_3 + 6144, 4);           // g11
        GEMM_PH(4, R0, lh2, 0, accg)           // P9: g9 (h2 new)
        ISSUE(R0, base_ih1, 4);                // g0' (next step)
        GEMM_PH(2, R1, lh2, 4, accg)           // P10: g10
        ISSUE(R1, base_hh1, 8);                // g1'
        GEMM_PH(2, R2, lh2, 6, accg)           // P11: g11
        ISSUE(R2, base_hh1 + 4096, 8);         // g2'

        // ---- u = sigmoid(gpre + b_g) ----
#pragma unroll
        for (int mt = 0; mt < 4; ++mt)
#pragma unroll
            for (int n2 = 0; n2 < 2; ++n2)
#pragma unroll
                for (int r = 0; r < 4; ++r)
                    u_reg[mt][n2][r] = fast_sigmoid(accg[mt][n2][r] + biasg_r[n2]);

        // ---- output projection: staged to LDS, dumped at kernel end ----
        float s1 = 0.f, s2 = 0.f;
#pragma unroll
        for (int c = 0; c < 4; ++c) {
            int kb = oseg * 64 + c * 16;
            bf16x8 hv1 = lds_ld8(lh1 + lds_addr(orow, kb));
            bf16x8 hv2 = lds_ld8(lh2 + lds_addr(orow, kb));
            const float* w1p = wo1 + oseg * 32 + c * 8;
            const float* w2p = wo2 + oseg * 32 + c * 8;
            float4 w10 = *(const float4*)w1p, w11 = *(const float4*)(w1p + 4);
            float4 w20 = *(const float4*)w2p, w21 = *(const float4*)(w2p + 4);
            s1 += (float)hv1[0] * w10.x + (float)hv1[1] * w10.y + (float)hv1[2] * w10.z + (float)hv1[3] * w10.w;
            s1 += (float)hv1[4] * w11.x + (float)hv1[5] * w11.y + (float)hv1[6] * w11.z + (float)hv1[7] * w11.w;
            s2 += (float)hv2[0] * w20.x + (float)hv2[1] * w20.y + (float)hv2[2] * w20.z + (float)hv2[3] * w20.w;
            s2 += (float)hv2[4] * w21.x + (float)hv2[5] * w21.y + (float)hv2[6] * w21.z + (float)hv2[7] * w21.w;
        }
        s1 += __shfl_xor(s1, 1, 8); s1 += __shfl_xor(s1, 2, 8); s1 += __shfl_xor(s1, 4, 8);
        s2 += __shfl_xor(s2, 1, 8); s2 += __shfl_xor(s2, 2, 8); s2 += __shfl_xor(s2, 4, 8);
        if (oseg == 0)
            lout[orow * TSTEPS + t] = fast_tanh(s1 + bo1) + fast_tanh(s2 + bo2);
    }

    // ---- epilogue: dump staged outputs, fully coalesced ----
    BAR();
    {
        float o[8];
#pragma unroll
        for (int i = 0; i < 8; ++i) o[i] = lout[tid * 8 + i];
        float* op = out + (size_t)b0 * TSTEPS + tid * 8;
        f32x4 o0 = {o[0], o[1], o[2], o[3]};
        f32x4 o1 = {o[4], o[5], o[6], o[7]};
        *(f32x4*)op = o0;
        *(f32x4*)(op + 4) = o1;
    }
}

extern "C" void kernel_launch(void* const* d_in, const int* in_sizes, int n_in,
                              void* d_out, int out_size, void* d_ws, size_t ws_size,
                              hipStream_t stream) {
    const float* x = (const float*)d_in[0];
    const float* W_ih1 = (const float*)d_in[1];
    const float* b_ih1 = (const float*)d_in[2];
    const float* W_hh1 = (const float*)d_in[3];
    const float* b_hh1 = (const float*)d_in[4];
    const float* W_ih2 = (const float*)d_in[5];
    const float* b_ih2 = (const float*)d_in[6];
    const float* W_hh2 = (const float*)d_in[7];
    const float* b_hh2 = (const float*)d_in[8];
    const float* W_o1 = (const float*)d_in[9];
    const float* b_o1 = (const float*)d_in[10];
    const float* W_o2 = (const float*)d_in[11];
    const float* b_o2 = (const float*)d_in[12];
    const float* W_g = (const float*)d_in[13];
    const float* b_g = (const float*)d_in[14];

    char* ws = (char*)d_ws;
    bf16_t* pw_ih1 = (bf16_t*)(ws + 0);        // 32768 B
    bf16_t* pw_hh1 = (bf16_t*)(ws + 32768);    // 131072 B
    bf16_t* pw_2a = (bf16_t*)(ws + 163840);    // 262144 B
    bf16_t* pw_2b = (bf16_t*)(ws + 425984);    // 131072 B
    bf16_t* pw_3 = (bf16_t*)(ws + 557056);     // 131072 B
    float* bias1 = (float*)(ws + 688128);
    float* bias2a = (float*)(ws + 689152);
    float* biasg = (float*)(ws + 690176);

    pack_w<<<32 * 2, 256, 0, stream>>>(W_ih1, W_ih1, 64, 64, 64, 0, 0, 2, pw_ih1);
    pack_w<<<32 * 8, 256, 0, stream>>>(W_hh1, W_hh1, 256, 256, 256, 0, 0, 8, pw_hh1);
    pack_w<<<32 * 16, 256, 0, stream>>>(W_ih2, W_hh2, 256, 256, 256, 0, 0, 16, pw_2a);
    pack_w<<<32 * 8, 256, 0, stream>>>(W_g, W_g, 256, 512, 512, 0, 0, 8, pw_2b);
    pack_w<<<32 * 8, 256, 0, stream>>>(W_g, W_g, 256, 512, 512, 256, 0, 8, pw_3);
    pack_bias<<<1, 256, 0, stream>>>(b_ih1, b_hh1, b_ih2, b_hh2, b_g, bias1, bias2a, biasg);

    rnn_main<<<NBLK, 512, 0, stream>>>(x, pw_ih1, pw_hh1, pw_2a, pw_2b, pw_3,
                                       bias1, bias2a, biasg, W_o1, b_o1, W_o2, b_o2,
                                       (float*)d_out);
}

// Round 8
// 2443.742 us; speedup vs baseline: 2.9593x; 2.9593x over previous
//
#include <hip/hip_runtime.h>
#include <hip/hip_bf16.h>

typedef __bf16 bf16_t;
typedef __bf16 bf16x8 __attribute__((ext_vector_type(8)));
typedef float f32x4 __attribute__((ext_vector_type(4)));
typedef int i32x4 __attribute__((ext_vector_type(4)));

#define HDIM 256
#define TSTEPS 64
#define DIN 64
#define BM 64
#define NBLK 256  // 16384 / 64

__device__ __forceinline__ float fast_tanh(float x) {
    float e = __builtin_amdgcn_exp2f(x * 2.8853900817779268f);
    return 1.0f - 2.0f * __builtin_amdgcn_rcpf(e + 1.0f);
}
__device__ __forceinline__ float fast_sigmoid(float x) {
    float e = __builtin_amdgcn_exp2f(-x * 1.4426950408889634f);
    return __builtin_amdgcn_rcpf(1.0f + e);
}

// swizzled LDS byte address for h tiles: row-major [64][256] bf16 (stride 512B)
__device__ __forceinline__ unsigned lds_addr(int row, int kb) {
    return (unsigned)(row * 512 + (kb ^ ((row & 7) << 4)));
}
// swizzled LDS byte address for x tile: row-major [64][64] bf16 (stride 128B)
__device__ __forceinline__ unsigned lx_addr(int row, int kb) {
    return (unsigned)(row * 128 + (kb ^ ((row & 7) << 4)));
}

__device__ __forceinline__ bf16x8 lds_ld8(const char* p) {
    return *(const bf16x8*)p;
}
__device__ __forceinline__ void lds_st1(char* p, bf16_t v) {
    *(bf16_t*)p = v;
}

// Raw barrier: waits LDS ops, does NOT drain vmcnt (weight loads stay in
// flight). The single asm blob with a "memory" clobber is the round-5 fix:
// IR-level memory ops (incl. plain LDS loads/stores) cannot be moved across
// it, and waitcnt+barrier can't be separated by MIR scheduling.
#define BAR()                                                       \
    do {                                                            \
        __builtin_amdgcn_sched_barrier(0);                          \
        asm volatile("s_waitcnt lgkmcnt(0)\n\ts_barrier" ::: "memory"); \
        __builtin_amdgcn_sched_barrier(0);                          \
    } while (0)

// ---------------- weight packing (prologue) ----------------
// Chunk layout (kc-major, n2-minor):
//   chunk = (wave*KC + kc)*2 + n2, element ((chunk)*64 + lane)*8 + i holds
//   W[n = (wave*2+n2)*16 + (lane&15)][k = kc*32 + (lane>>4)*8 + i]
__global__ void pack_w(const float* __restrict__ s0, const float* __restrict__ s1,
                       int ksplit, int stride0, int stride1, int off0, int off1,
                       int KC, bf16_t* __restrict__ dst) {
    int idx = blockIdx.x * 256 + threadIdx.x;
    int total = 256 * KC * 32;
    if (idx >= total) return;
    int i = idx & 7;
    int lane = (idx >> 3) & 63;
    int chunk = idx >> 9;
    int n2 = chunk & 1;
    int rest = chunk >> 1;
    int kc = rest % KC, wv = rest / KC;
    int nt = wv * 2 + n2;
    int n = nt * 16 + (lane & 15);
    int k = kc * 32 + ((lane >> 4) * 8) + i;
    float v = (k < ksplit) ? s0[n * stride0 + off0 + k]
                           : s1[n * stride1 + off1 + (k - ksplit)];
    dst[idx] = (bf16_t)v;
}

__global__ void pack_bias(const float* __restrict__ b_ih1, const float* __restrict__ b_hh1,
                          const float* __restrict__ b_ih2, const float* __restrict__ b_hh2,
                          const float* __restrict__ b_g,
                          float* __restrict__ bias1, float* __restrict__ bias2a,
                          float* __restrict__ biasg) {
    int j = threadIdx.x;
    bias1[j] = b_ih1[j] + b_hh1[j];
    bias2a[j] = b_ih2[j] + b_hh2[j];
    biasg[j] = b_g[j];
}

#define ISSUE(BUF, PB, N)                                            \
    _Pragma("unroll") for (int c = 0; c < (N); ++c)                  \
        BUF[c] = *(const bf16x8*)((PB) + c * 512 + (lane << 3));

#define GEMM_PH(NKK, BUF, ASRC, KC0, ACC)                                             \
    _Pragma("unroll") for (int kk = 0; kk < (NKK); ++kk) {                            \
        bf16x8 a_[4];                                                                 \
        _Pragma("unroll") for (int mt = 0; mt < 4; ++mt)                              \
            a_[mt] = lds_ld8((ASRC) + lds_addr(mt * 16 + l15,                         \
                                               ((KC0) + kk) * 64 + l4 * 16));         \
        _Pragma("unroll") for (int mt = 0; mt < 4; ++mt) {                            \
            ACC[mt][0] = __builtin_amdgcn_mfma_f32_16x16x32_bf16(a_[mt], BUF[kk * 2 + 0], ACC[mt][0], 0, 0, 0); \
            ACC[mt][1] = __builtin_amdgcn_mfma_f32_16x16x32_bf16(a_[mt], BUF[kk * 2 + 1], ACC[mt][1], 0, 0, 0); \
        }                                                                             \
    }

// ---------------- main persistent RNN kernel ----------------
__global__ __launch_bounds__(512, 1) void rnn_main(
    const float* __restrict__ x,
    const bf16_t* __restrict__ pw_ih1,   // N=256 K=64  (KC=2)
    const bf16_t* __restrict__ pw_hh1,   // N=256 K=256 (KC=8)
    const bf16_t* __restrict__ pw_2a,    // N=256 K=512 (KC=16): k<256 W_ih2, k>=256 W_hh2
    const bf16_t* __restrict__ pw_2b,    // N=256 K=256 (KC=8): Wg[:, 0:256]
    const bf16_t* __restrict__ pw_3,     // N=256 K=256 (KC=8): Wg[:, 256:512]
    const float* __restrict__ bias1v, const float* __restrict__ bias2av,
    const float* __restrict__ biasgv,
    const float* __restrict__ wo1, const float* __restrict__ bo1p,
    const float* __restrict__ wo2, const float* __restrict__ bo2p,
    unsigned* __restrict__ gsync,
    float* __restrict__ out) {
    __shared__ char lds[90112];
    char* lh1 = lds;            // [64][256] bf16 swizzled
    char* lh2 = lds + 32768;    // [64][256] bf16 swizzled
    char* lx  = lds + 65536;    // [64][64]  bf16 swizzled (x tile)
    float* lout = (float*)(lds + 73728);  // [64][64] f32 linear (out staging)

    const int tid = threadIdx.x;
    const int wave = tid >> 6, lane = tid & 63;
    const int l15 = lane & 15, l4 = lane >> 4;
    const int b0 = blockIdx.x * BM;

    {   // zero h1, h2 in LDS (initial state)
        i32x4 z = {0, 0, 0, 0};
        for (int i = tid; i < 4096; i += 512) ((i32x4*)lds)[i] = z;
    }

    f32x4 u_reg[4][2];
#pragma unroll
    for (int mt = 0; mt < 4; ++mt)
#pragma unroll
        for (int n2 = 0; n2 < 2; ++n2) u_reg[mt][n2] = (f32x4){1.f, 1.f, 1.f, 1.f};

    float bias1_r[2], bias2a_r[2], biasg_r[2];
#pragma unroll
    for (int n2 = 0; n2 < 2; ++n2) {
        int col = wave * 32 + n2 * 16 + l15;
        bias1_r[n2] = bias1v[col];
        bias2a_r[n2] = bias2av[col];
        biasg_r[n2] = biasgv[col];
    }
    const float bo1 = bo1p[0], bo2 = bo2p[0];
    const int orow = tid >> 3, oseg = tid & 7;
    const int xrow = tid >> 3, xc16 = (tid & 7) * 16;
    const float* xbase = x + (size_t)(b0 + xrow) * (TSTEPS * DIN) + (tid & 7) * 8;

    // per-wave contiguous stream bases (element offsets)
    const bf16_t* base_ih1 = pw_ih1 + wave * 2048;    // 4 chunks
    const bf16_t* base_hh1 = pw_hh1 + wave * 8192;    // 16 chunks
    const bf16_t* base_2a  = pw_2a  + wave * 16384;   // 32 chunks
    const bf16_t* base_2b  = pw_2b  + wave * 8192;    // 16 chunks
    const bf16_t* base_3   = pw_3   + wave * 8192;    // 16 chunks

    // ring-3 weight buffers; 12 groups/step, consume g then issue g+3
    bf16x8 R0[8], R1[8], R2[8];

    // prologue: stage x(t=0) into lx; warm the ring (g0,g1,g2)
    {
        f32x4 xv0 = __builtin_nontemporal_load((const f32x4*)xbase);
        f32x4 xv1 = __builtin_nontemporal_load((const f32x4*)(xbase + 4));
        bf16x8 xa;
        xa[0] = (bf16_t)xv0[0]; xa[1] = (bf16_t)xv0[1]; xa[2] = (bf16_t)xv0[2]; xa[3] = (bf16_t)xv0[3];
        xa[4] = (bf16_t)xv1[0]; xa[5] = (bf16_t)xv1[1]; xa[6] = (bf16_t)xv1[2]; xa[7] = (bf16_t)xv1[3];
        *(bf16x8*)(lx + lx_addr(xrow, xc16)) = xa;
    }
    ISSUE(R0, base_ih1, 4);            // g0
    ISSUE(R1, base_hh1, 8);            // g1
    ISSUE(R2, base_hh1 + 4096, 8);     // g2
    BAR();

    for (int t = 0; t < TSTEPS; ++t) {
        // ---- P0: consume R0=g0 (x-GEMM, A from lx) | issue g3 ----
        f32x4 acc[4][2];
#pragma unroll
        for (int mt = 0; mt < 4; ++mt)
#pragma unroll
            for (int n2 = 0; n2 < 2; ++n2) acc[mt][n2] = (f32x4){0.f, 0.f, 0.f, 0.f};
#pragma unroll
        for (int kk = 0; kk < 2; ++kk) {
            bf16x8 a_[4];
#pragma unroll
            for (int mt = 0; mt < 4; ++mt)
                a_[mt] = lds_ld8(lx + lx_addr(mt * 16 + l15, kk * 64 + l4 * 16));
#pragma unroll
            for (int mt = 0; mt < 4; ++mt) {
                acc[mt][0] = __builtin_amdgcn_mfma_f32_16x16x32_bf16(a_[mt], R0[kk * 2 + 0], acc[mt][0], 0, 0, 0);
                acc[mt][1] = __builtin_amdgcn_mfma_f32_16x16x32_bf16(a_[mt], R0[kk * 2 + 1], acc[mt][1], 0, 0, 0);
            }
        }
        ISSUE(R0, base_2a, 8);                 // g3
        // issue x(t+1) global loads (consumed after the lh2 window)
        f32x4 xv0, xv1;
        {
            int tn = t + 1; if (tn > TSTEPS - 1) tn = TSTEPS - 1;
            const float* xp = xbase + tn * DIN;
            xv0 = __builtin_nontemporal_load((const f32x4*)xp);
            xv1 = __builtin_nontemporal_load((const f32x4*)(xp + 4));
        }
        // ---- P1: consume R1=g1 (hh1 kc0-3) | issue g4 ----
        GEMM_PH(4, R1, lh1, 0, acc)
        ISSUE(R1, base_2a + 4096, 8);          // g4
        // ---- P2: consume R2=g2 (hh1 kc4-7) | issue g5 ----
        GEMM_PH(4, R2, lh1, 4, acc)
        ISSUE(R2, base_2a + 8192, 8);          // g5

        // ---- h1 epilogue ----
        float h1n[4][2][4];
#pragma unroll
        for (int mt = 0; mt < 4; ++mt)
#pragma unroll
            for (int n2 = 0; n2 < 2; ++n2)
#pragma unroll
                for (int r = 0; r < 4; ++r)
                    h1n[mt][n2][r] = fast_tanh(acc[mt][n2][r] + bias1_r[n2]);
        BAR();  // all waves done reading old lh1 / lx / prev out-proj
#pragma unroll
        for (int mt = 0; mt < 4; ++mt)
#pragma unroll
            for (int n2 = 0; n2 < 2; ++n2)
#pragma unroll
                for (int r = 0; r < 4; ++r)
                    lds_st1(lh1 + lds_addr(mt * 16 + l4 * 4 + r,
                                           (wave * 32 + n2 * 16 + l15) * 2), (bf16_t)h1n[mt][n2][r]);
        BAR();  // h1new visible

        // ---- P3..P6: GEMM2a (K=512: lh1new kc0-7, lh2old kc0-7) ----
        f32x4 accz[4][2];
#pragma unroll
        for (int mt = 0; mt < 4; ++mt)
#pragma unroll
            for (int n2 = 0; n2 < 2; ++n2) accz[mt][n2] = (f32x4){0.f, 0.f, 0.f, 0.f};
        GEMM_PH(4, R0, lh1, 0, accz)           // P3: g3
        ISSUE(R0, base_2a + 12288, 8);         // g6
        GEMM_PH(4, R1, lh1, 4, accz)           // P4: g4
        ISSUE(R1, base_2b, 8);                 // g7
        GEMM_PH(4, R2, lh2, 0, accz)           // P5: g5 (h2 old)
        ISSUE(R2, base_2b + 4096, 8);          // g8
        GEMM_PH(4, R0, lh2, 4, accz)           // P6: g6 (h2 old)
        ISSUE(R0, base_3, 8);                  // g9

        // ---- blend: z2 = tanh(accz+b); h2n = u*z2 + (1-u)*h2old (h2old from LDS) ----
        float h2n[4][2][4];
#pragma unroll
        for (int mt = 0; mt < 4; ++mt)
#pragma unroll
            for (int n2 = 0; n2 < 2; ++n2)
#pragma unroll
                for (int r = 0; r < 4; ++r) {
                    float z2 = fast_tanh(accz[mt][n2][r] + bias2a_r[n2]);
                    float h2o = (float)*(const bf16_t*)(lh2 + lds_addr(mt * 16 + l4 * 4 + r,
                                                                       (wave * 32 + n2 * 16 + l15) * 2));
                    float un = u_reg[mt][n2][r];
                    h2n[mt][n2][r] = un * z2 + (1.f - un) * h2o;
                }
        BAR();  // all waves done reading old lh2 (and lx from P0)
        // write h2new to lh2, x(t+1) to lx (visible after next BAR)
#pragma unroll
        for (int mt = 0; mt < 4; ++mt)
#pragma unroll
            for (int n2 = 0; n2 < 2; ++n2)
#pragma unroll
                for (int r = 0; r < 4; ++r)
                    lds_st1(lh2 + lds_addr(mt * 16 + l4 * 4 + r,
                                           (wave * 32 + n2 * 16 + l15) * 2), (bf16_t)h2n[mt][n2][r]);
        {
            bf16x8 xa;
            xa[0] = (bf16_t)xv0[0]; xa[1] = (bf16_t)xv0[1]; xa[2] = (bf16_t)xv0[2]; xa[3] = (bf16_t)xv0[3];
            xa[4] = (bf16_t)xv1[0]; xa[5] = (bf16_t)xv1[1]; xa[6] = (bf16_t)xv1[2]; xa[7] = (bf16_t)xv1[3];
            *(bf16x8*)(lx + lx_addr(xrow, xc16)) = xa;
        }

        // ---- P7 (inside write window, reads lh1 only): consume g7 | issue g10 ----
        f32x4 accg[4][2];
#pragma unroll
        for (int mt = 0; mt < 4; ++mt)
#pragma unroll
            for (int n2 = 0; n2 < 2; ++n2) accg[mt][n2] = (f32x4){0.f, 0.f, 0.f, 0.f};
        GEMM_PH(4, R1, lh1, 0, accg)           // g7
        ISSUE(R1, base_3 + 4096, 4);           // g10
        BAR();  // h2new + x(t+1) visible

        // ---- P8..P11 ----
        GEMM_PH(4, R2, lh1, 4, accg)           // P8: g8
        ISSUE(R2, base_3 + 6144, 4);           // g11
        GEMM_PH(4, R0, lh2, 0, accg)           // P9: g9 (h2 new)
        ISSUE(R0, base_ih1, 4);                // g0' (next step)
        GEMM_PH(2, R1, lh2, 4, accg)           // P10: g10
        ISSUE(R1, base_hh1, 8);                // g1'
        GEMM_PH(2, R2, lh2, 6, accg)           // P11: g11
        ISSUE(R2, base_hh1 + 4096, 8);         // g2'

        // ---- u = sigmoid(gpre + b_g) ----
#pragma unroll
        for (int mt = 0; mt < 4; ++mt)
#pragma unroll
            for (int n2 = 0; n2 < 2; ++n2)
#pragma unroll
                for (int r = 0; r < 4; ++r)
                    u_reg[mt][n2][r] = fast_sigmoid(accg[mt][n2][r] + biasg_r[n2]);

        // ---- output projection: staged to LDS, dumped at kernel end ----
        float s1 = 0.f, s2 = 0.f;
#pragma unroll
        for (int c = 0; c < 4; ++c) {
            int kb = oseg * 64 + c * 16;
            bf16x8 hv1 = lds_ld8(lh1 + lds_addr(orow, kb));
            bf16x8 hv2 = lds_ld8(lh2 + lds_addr(orow, kb));
            const float* w1p = wo1 + oseg * 32 + c * 8;
            const float* w2p = wo2 + oseg * 32 + c * 8;
            float4 w10 = *(const float4*)w1p, w11 = *(const float4*)(w1p + 4);
            float4 w20 = *(const float4*)w2p, w21 = *(const float4*)(w2p + 4);
            s1 += (float)hv1[0] * w10.x + (float)hv1[1] * w10.y + (float)hv1[2] * w10.z + (float)hv1[3] * w10.w;
            s1 += (float)hv1[4] * w11.x + (float)hv1[5] * w11.y + (float)hv1[6] * w11.z + (float)hv1[7] * w11.w;
            s2 += (float)hv2[0] * w20.x + (float)hv2[1] * w20.y + (float)hv2[2] * w20.z + (float)hv2[3] * w20.w;
            s2 += (float)hv2[4] * w21.x + (float)hv2[5] * w21.y + (float)hv2[6] * w21.z + (float)hv2[7] * w21.w;
        }
        s1 += __shfl_xor(s1, 1, 8); s1 += __shfl_xor(s1, 2, 8); s1 += __shfl_xor(s1, 4, 8);
        s2 += __shfl_xor(s2, 1, 8); s2 += __shfl_xor(s2, 2, 8); s2 += __shfl_xor(s2, 4, 8);
        if (oseg == 0)
            lout[orow * TSTEPS + t] = fast_tanh(s1 + bo1) + fast_tanh(s2 + bo2);

        // ---- soft grid barrier: phase-align all 256 blocks per step ----
        // Perf-only (no data crosses it): keeps the shared weight stream
        // phase-coherent so each L2 line is reused by all 32 blocks/XCD
        // within its ~10us lifetime. Bounded spin -> no deadlock even under
        // pathological dispatch; correctness never depends on it.
        if (tid == 0) {
            __hip_atomic_fetch_add(gsync, 1u, __ATOMIC_RELAXED, __HIP_MEMORY_SCOPE_AGENT);
            unsigned target = (unsigned)NBLK * (unsigned)(t + 1);
            int guard = 0;
            while (__hip_atomic_load(gsync, __ATOMIC_RELAXED, __HIP_MEMORY_SCOPE_AGENT) < target
                   && guard < 4000) {
                ++guard;
                __builtin_amdgcn_s_sleep(1);
            }
        }
        BAR();  // rest of the block waits for thread 0
    }

    // ---- epilogue: dump staged outputs, fully coalesced ----
    {
        const float* lp = lout + tid * 8;
        f32x4 o0 = {lp[0], lp[1], lp[2], lp[3]};
        f32x4 o1 = {lp[4], lp[5], lp[6], lp[7]};
        float* op = out + (size_t)b0 * TSTEPS + tid * 8;
        *(f32x4*)op = o0;
        *(f32x4*)(op + 4) = o1;
    }
}

extern "C" void kernel_launch(void* const* d_in, const int* in_sizes, int n_in,
                              void* d_out, int out_size, void* d_ws, size_t ws_size,
                              hipStream_t stream) {
    const float* x = (const float*)d_in[0];
    const float* W_ih1 = (const float*)d_in[1];
    const float* b_ih1 = (const float*)d_in[2];
    const float* W_hh1 = (const float*)d_in[3];
    const float* b_hh1 = (const float*)d_in[4];
    const float* W_ih2 = (const float*)d_in[5];
    const float* b_ih2 = (const float*)d_in[6];
    const float* W_hh2 = (const float*)d_in[7];
    const float* b_hh2 = (const float*)d_in[8];
    const float* W_o1 = (const float*)d_in[9];
    const float* b_o1 = (const float*)d_in[10];
    const float* W_o2 = (const float*)d_in[11];
    const float* b_o2 = (const float*)d_in[12];
    const float* W_g = (const float*)d_in[13];
    const float* b_g = (const float*)d_in[14];

    char* ws = (char*)d_ws;
    bf16_t* pw_ih1 = (bf16_t*)(ws + 0);        // 32768 B
    bf16_t* pw_hh1 = (bf16_t*)(ws + 32768);    // 131072 B
    bf16_t* pw_2a = (bf16_t*)(ws + 163840);    // 262144 B
    bf16_t* pw_2b = (bf16_t*)(ws + 425984);    // 131072 B
    bf16_t* pw_3 = (bf16_t*)(ws + 557056);     // 131072 B
    float* bias1 = (float*)(ws + 688128);
    float* bias2a = (float*)(ws + 689152);
    float* biasg = (float*)(ws + 690176);
    unsigned* gsync = (unsigned*)(ws + 692224);  // 128 B sync region

    pack_w<<<32 * 2, 256, 0, stream>>>(W_ih1, W_ih1, 64, 64, 64, 0, 0, 2, pw_ih1);
    pack_w<<<32 * 8, 256, 0, stream>>>(W_hh1, W_hh1, 256, 256, 256, 0, 0, 8, pw_hh1);
    pack_w<<<32 * 16, 256, 0, stream>>>(W_ih2, W_hh2, 256, 256, 256, 0, 0, 16, pw_2a);
    pack_w<<<32 * 8, 256, 0, stream>>>(W_g, W_g, 256, 512, 512, 0, 0, 8, pw_2b);
    pack_w<<<32 * 8, 256, 0, stream>>>(W_g, W_g, 256, 512, 512, 256, 0, 8, pw_3);
    pack_bias<<<1, 256, 0, stream>>>(b_ih1, b_hh1, b_ih2, b_hh2, b_g, bias1, bias2a, biasg);
    hipMemsetAsync(gsync, 0, 128, stream);  // reset soft-barrier counter each call

    rnn_main<<<NBLK, 512, 0, stream>>>(x, pw_ih1, pw_hh1, pw_2a, pw_2b, pw_3,
                                       bias1, bias2a, biasg, W_o1, b_o1, W_o2, b_o2,
                                       gsync, (float*)d_out);
}

// Round 9
// 1990.240 us; speedup vs baseline: 3.6337x; 1.2279x over previous
//
#include <hip/hip_runtime.h>
#include <hip/hip_bf16.h>

typedef __bf16 bf16_t;
typedef __bf16 bf16x8 __attribute__((ext_vector_type(8)));
typedef float f32x4 __attribute__((ext_vector_type(4)));
typedef int i32x4 __attribute__((ext_vector_type(4)));

#define HDIM 256
#define TSTEPS 64
#define DIN 64
#define BM 64
#define NBLK 256  // 16384 / 64

__device__ __forceinline__ float fast_tanh(float x) {
    float e = __builtin_amdgcn_exp2f(x * 2.8853900817779268f);
    return 1.0f - 2.0f * __builtin_amdgcn_rcpf(e + 1.0f);
}
__device__ __forceinline__ float fast_sigmoid(float x) {
    float e = __builtin_amdgcn_exp2f(-x * 1.4426950408889634f);
    return __builtin_amdgcn_rcpf(1.0f + e);
}

// swizzled LDS byte address for h tiles: row-major [64][256] bf16 (stride 512B)
__device__ __forceinline__ unsigned lds_addr(int row, int kb) {
    return (unsigned)(row * 512 + (kb ^ ((row & 7) << 4)));
}
// swizzled LDS byte address for x tile: row-major [64][64] bf16 (stride 128B)
__device__ __forceinline__ unsigned lx_addr(int row, int kb) {
    return (unsigned)(row * 128 + (kb ^ ((row & 7) << 4)));
}

__device__ __forceinline__ bf16x8 lds_ld8(const char* p) {
    return *(const bf16x8*)p;
}
__device__ __forceinline__ void lds_st1(char* p, bf16_t v) {
    *(bf16_t*)p = v;
}

// Raw barrier: waits LDS ops, does NOT drain vmcnt (weight loads stay in
// flight). Single asm blob with "memory" clobber: IR-level memory ops can't
// cross it, and waitcnt+barrier can't be separated by MIR scheduling.
#define BAR()                                                       \
    do {                                                            \
        __builtin_amdgcn_sched_barrier(0);                          \
        asm volatile("s_waitcnt lgkmcnt(0)\n\ts_barrier" ::: "memory"); \
        __builtin_amdgcn_sched_barrier(0);                          \
    } while (0)

// ---------------- weight packing (prologue) ----------------
// Chunk layout (kc-major, n2-minor):
//   chunk = (wave*KC + kc)*2 + n2, element ((chunk)*64 + lane)*8 + i holds
//   W[n = (wave*2+n2)*16 + (lane&15)][k = kc*32 + (lane>>4)*8 + i]
__global__ void pack_w(const float* __restrict__ s0, const float* __restrict__ s1,
                       int ksplit, int stride0, int stride1, int off0, int off1,
                       int KC, bf16_t* __restrict__ dst) {
    int idx = blockIdx.x * 256 + threadIdx.x;
    int total = 256 * KC * 32;
    if (idx >= total) return;
    int i = idx & 7;
    int lane = (idx >> 3) & 63;
    int chunk = idx >> 9;
    int n2 = chunk & 1;
    int rest = chunk >> 1;
    int kc = rest % KC, wv = rest / KC;
    int nt = wv * 2 + n2;
    int n = nt * 16 + (lane & 15);
    int k = kc * 32 + ((lane >> 4) * 8) + i;
    float v = (k < ksplit) ? s0[n * stride0 + off0 + k]
                           : s1[n * stride1 + off1 + (k - ksplit)];
    dst[idx] = (bf16_t)v;
}

__global__ void pack_bias(const float* __restrict__ b_ih1, const float* __restrict__ b_hh1,
                          const float* __restrict__ b_ih2, const float* __restrict__ b_hh2,
                          const float* __restrict__ b_g,
                          float* __restrict__ bias1, float* __restrict__ bias2a,
                          float* __restrict__ biasg) {
    int j = threadIdx.x;
    bias1[j] = b_ih1[j] + b_hh1[j];
    bias2a[j] = b_ih2[j] + b_hh2[j];
    biasg[j] = b_g[j];
}

#define ISSUE(BUF, PB, N)                                            \
    _Pragma("unroll") for (int c = 0; c < (N); ++c)                  \
        BUF[c] = *(const bf16x8*)((PB) + c * 512 + (lane << 3));

#define GEMM_PH(NKK, BUF, ASRC, KC0, ACC)                                             \
    _Pragma("unroll") for (int kk = 0; kk < (NKK); ++kk) {                            \
        bf16x8 a_[4];                                                                 \
        _Pragma("unroll") for (int mt = 0; mt < 4; ++mt)                              \
            a_[mt] = lds_ld8((ASRC) + lds_addr(mt * 16 + l15,                         \
                                               ((KC0) + kk) * 64 + l4 * 16));         \
        _Pragma("unroll") for (int mt = 0; mt < 4; ++mt) {                            \
            ACC[mt][0] = __builtin_amdgcn_mfma_f32_16x16x32_bf16(a_[mt], BUF[kk * 2 + 0], ACC[mt][0], 0, 0, 0); \
            ACC[mt][1] = __builtin_amdgcn_mfma_f32_16x16x32_bf16(a_[mt], BUF[kk * 2 + 1], ACC[mt][1], 0, 0, 0); \
        }                                                                             \
    }

// ---------------- main persistent RNN kernel ----------------
__global__ __launch_bounds__(512, 1) void rnn_main(
    const float* __restrict__ x,
    const bf16_t* __restrict__ pw_ih1,   // N=256 K=64  (KC=2)
    const bf16_t* __restrict__ pw_hh1,   // N=256 K=256 (KC=8)
    const bf16_t* __restrict__ pw_2a,    // N=256 K=512 (KC=16): k<256 W_ih2, k>=256 W_hh2
    const bf16_t* __restrict__ pw_2b,    // N=256 K=256 (KC=8): Wg[:, 0:256]
    const bf16_t* __restrict__ pw_3,     // N=256 K=256 (KC=8): Wg[:, 256:512]
    const float* __restrict__ bias1v, const float* __restrict__ bias2av,
    const float* __restrict__ biasgv,
    const float* __restrict__ wo1, const float* __restrict__ bo1p,
    const float* __restrict__ wo2, const float* __restrict__ bo2p,
    unsigned* __restrict__ gsync,
    float* __restrict__ out) {
    __shared__ char lds[90112];
    char* lh1 = lds;            // [64][256] bf16 swizzled
    char* lh2 = lds + 32768;    // [64][256] bf16 swizzled
    char* lx  = lds + 65536;    // [64][64]  bf16 swizzled (x tile)
    float* lout = (float*)(lds + 73728);  // [64][64] f32 linear (out staging)

    const int tid = threadIdx.x;
    const int wave = tid >> 6, lane = tid & 63;
    const int l15 = lane & 15, l4 = lane >> 4;
    const int b0 = blockIdx.x * BM;
    // 8 barrier groups of exactly 32 blocks each (blockIdx&7 matches the
    // XCD round-robin mapping, so each group's counter stays L2-local).
    unsigned* gc = gsync + (blockIdx.x & 7) * 32;  // 128B-spaced counters

    {   // zero h1, h2 in LDS (initial state)
        i32x4 z = {0, 0, 0, 0};
        for (int i = tid; i < 4096; i += 512) ((i32x4*)lds)[i] = z;
    }

    f32x4 u_reg[4][2];
#pragma unroll
    for (int mt = 0; mt < 4; ++mt)
#pragma unroll
        for (int n2 = 0; n2 < 2; ++n2) u_reg[mt][n2] = (f32x4){1.f, 1.f, 1.f, 1.f};

    float bias1_r[2], bias2a_r[2], biasg_r[2];
#pragma unroll
    for (int n2 = 0; n2 < 2; ++n2) {
        int col = wave * 32 + n2 * 16 + l15;
        bias1_r[n2] = bias1v[col];
        bias2a_r[n2] = bias2av[col];
        biasg_r[n2] = biasgv[col];
    }
    const float bo1 = bo1p[0], bo2 = bo2p[0];
    const int orow = tid >> 3, oseg = tid & 7;
    const int xrow = tid >> 3, xc16 = (tid & 7) * 16;
    const float* xbase = x + (size_t)(b0 + xrow) * (TSTEPS * DIN) + (tid & 7) * 8;

    // per-wave contiguous stream bases (element offsets)
    const bf16_t* base_ih1 = pw_ih1 + wave * 2048;    // 4 chunks
    const bf16_t* base_hh1 = pw_hh1 + wave * 8192;    // 16 chunks
    const bf16_t* base_2a  = pw_2a  + wave * 16384;   // 32 chunks
    const bf16_t* base_2b  = pw_2b  + wave * 8192;    // 16 chunks
    const bf16_t* base_3   = pw_3   + wave * 8192;    // 16 chunks

    // ring-3 weight buffers; 12 groups/step, consume g then issue g+3
    bf16x8 R0[8], R1[8], R2[8];

    // prologue: stage x(t=0) into lx; warm the ring (g0,g1,g2)
    {
        f32x4 xv0 = __builtin_nontemporal_load((const f32x4*)xbase);
        f32x4 xv1 = __builtin_nontemporal_load((const f32x4*)(xbase + 4));
        bf16x8 xa;
        xa[0] = (bf16_t)xv0[0]; xa[1] = (bf16_t)xv0[1]; xa[2] = (bf16_t)xv0[2]; xa[3] = (bf16_t)xv0[3];
        xa[4] = (bf16_t)xv1[0]; xa[5] = (bf16_t)xv1[1]; xa[6] = (bf16_t)xv1[2]; xa[7] = (bf16_t)xv1[3];
        *(bf16x8*)(lx + lx_addr(xrow, xc16)) = xa;
    }
    ISSUE(R0, base_ih1, 4);            // g0
    ISSUE(R1, base_hh1, 8);            // g1
    ISSUE(R2, base_hh1 + 4096, 8);     // g2
    BAR();

    for (int t = 0; t < TSTEPS; ++t) {
        // ---- P0: consume R0=g0 (x-GEMM, A from lx) | issue g3 ----
        f32x4 acc[4][2];
#pragma unroll
        for (int mt = 0; mt < 4; ++mt)
#pragma unroll
            for (int n2 = 0; n2 < 2; ++n2) acc[mt][n2] = (f32x4){0.f, 0.f, 0.f, 0.f};
#pragma unroll
        for (int kk = 0; kk < 2; ++kk) {
            bf16x8 a_[4];
#pragma unroll
            for (int mt = 0; mt < 4; ++mt)
                a_[mt] = lds_ld8(lx + lx_addr(mt * 16 + l15, kk * 64 + l4 * 16));
#pragma unroll
            for (int mt = 0; mt < 4; ++mt) {
                acc[mt][0] = __builtin_amdgcn_mfma_f32_16x16x32_bf16(a_[mt], R0[kk * 2 + 0], acc[mt][0], 0, 0, 0);
                acc[mt][1] = __builtin_amdgcn_mfma_f32_16x16x32_bf16(a_[mt], R0[kk * 2 + 1], acc[mt][1], 0, 0, 0);
            }
        }
        ISSUE(R0, base_2a, 8);                 // g3
        // issue x(t+1) global loads (consumed after the lh2 window)
        f32x4 xv0, xv1;
        {
            int tn = t + 1; if (tn > TSTEPS - 1) tn = TSTEPS - 1;
            const float* xp = xbase + tn * DIN;
            xv0 = __builtin_nontemporal_load((const f32x4*)xp);
            xv1 = __builtin_nontemporal_load((const f32x4*)(xp + 4));
        }
        // ---- P1: consume R1=g1 (hh1 kc0-3) | issue g4 ----
        GEMM_PH(4, R1, lh1, 0, acc)
        ISSUE(R1, base_2a + 4096, 8);          // g4
        // ---- P2: consume R2=g2 (hh1 kc4-7) | issue g5 ----
        GEMM_PH(4, R2, lh1, 4, acc)
        ISSUE(R2, base_2a + 8192, 8);          // g5

        // ---- h1 epilogue ----
        float h1n[4][2][4];
#pragma unroll
        for (int mt = 0; mt < 4; ++mt)
#pragma unroll
            for (int n2 = 0; n2 < 2; ++n2)
#pragma unroll
                for (int r = 0; r < 4; ++r)
                    h1n[mt][n2][r] = fast_tanh(acc[mt][n2][r] + bias1_r[n2]);
        BAR();  // all waves done reading old lh1 / lx / prev out-proj
#pragma unroll
        for (int mt = 0; mt < 4; ++mt)
#pragma unroll
            for (int n2 = 0; n2 < 2; ++n2)
#pragma unroll
                for (int r = 0; r < 4; ++r)
                    lds_st1(lh1 + lds_addr(mt * 16 + l4 * 4 + r,
                                           (wave * 32 + n2 * 16 + l15) * 2), (bf16_t)h1n[mt][n2][r]);
        BAR();  // h1new visible

        // ---- P3..P6: GEMM2a (K=512: lh1new kc0-7, lh2old kc0-7) ----
        f32x4 accz[4][2];
#pragma unroll
        for (int mt = 0; mt < 4; ++mt)
#pragma unroll
            for (int n2 = 0; n2 < 2; ++n2) accz[mt][n2] = (f32x4){0.f, 0.f, 0.f, 0.f};
        GEMM_PH(4, R0, lh1, 0, accz)           // P3: g3
        ISSUE(R0, base_2a + 12288, 8);         // g6
        GEMM_PH(4, R1, lh1, 4, accz)           // P4: g4
        ISSUE(R1, base_2b, 8);                 // g7
        GEMM_PH(4, R2, lh2, 0, accz)           // P5: g5 (h2 old)
        ISSUE(R2, base_2b + 4096, 8);          // g8
        GEMM_PH(4, R0, lh2, 4, accz)           // P6: g6 (h2 old)
        ISSUE(R0, base_3, 8);                  // g9

        // ---- blend: z2 = tanh(accz+b); h2n = u*z2 + (1-u)*h2old (h2old from LDS) ----
        float h2n[4][2][4];
#pragma unroll
        for (int mt = 0; mt < 4; ++mt)
#pragma unroll
            for (int n2 = 0; n2 < 2; ++n2)
#pragma unroll
                for (int r = 0; r < 4; ++r) {
                    float z2 = fast_tanh(accz[mt][n2][r] + bias2a_r[n2]);
                    float h2o = (float)*(const bf16_t*)(lh2 + lds_addr(mt * 16 + l4 * 4 + r,
                                                                       (wave * 32 + n2 * 16 + l15) * 2));
                    float un = u_reg[mt][n2][r];
                    h2n[mt][n2][r] = un * z2 + (1.f - un) * h2o;
                }
        BAR();  // all waves done reading old lh2 (and lx from P0)
        // write h2new to lh2, x(t+1) to lx (visible after next BAR)
#pragma unroll
        for (int mt = 0; mt < 4; ++mt)
#pragma unroll
            for (int n2 = 0; n2 < 2; ++n2)
#pragma unroll
                for (int r = 0; r < 4; ++r)
                    lds_st1(lh2 + lds_addr(mt * 16 + l4 * 4 + r,
                                           (wave * 32 + n2 * 16 + l15) * 2), (bf16_t)h2n[mt][n2][r]);
        {
            bf16x8 xa;
            xa[0] = (bf16_t)xv0[0]; xa[1] = (bf16_t)xv0[1]; xa[2] = (bf16_t)xv0[2]; xa[3] = (bf16_t)xv0[3];
            xa[4] = (bf16_t)xv1[0]; xa[5] = (bf16_t)xv1[1]; xa[6] = (bf16_t)xv1[2]; xa[7] = (bf16_t)xv1[3];
            *(bf16x8*)(lx + lx_addr(xrow, xc16)) = xa;
        }

        // ---- P7 (inside write window, reads lh1 only): consume g7 | issue g10 ----
        f32x4 accg[4][2];
#pragma unroll
        for (int mt = 0; mt < 4; ++mt)
#pragma unroll
            for (int n2 = 0; n2 < 2; ++n2) accg[mt][n2] = (f32x4){0.f, 0.f, 0.f, 0.f};
        GEMM_PH(4, R1, lh1, 0, accg)           // g7
        ISSUE(R1, base_3 + 4096, 4);           // g10
        BAR();  // h2new + x(t+1) visible

        // ---- soft-barrier ARRIVE (overlaps with P8..P11 + out-proj) ----
        if (tid == 0)
            __hip_atomic_fetch_add(gc, 1u, __ATOMIC_RELAXED, __HIP_MEMORY_SCOPE_AGENT);

        // ---- P8..P11 ----
        GEMM_PH(4, R2, lh1, 4, accg)           // P8: g8
        ISSUE(R2, base_3 + 6144, 4);           // g11
        GEMM_PH(4, R0, lh2, 0, accg)           // P9: g9 (h2 new)
        ISSUE(R0, base_ih1, 4);                // g0' (next step)
        GEMM_PH(2, R1, lh2, 4, accg)           // P10: g10
        ISSUE(R1, base_hh1, 8);                // g1'
        GEMM_PH(2, R2, lh2, 6, accg)           // P11: g11
        ISSUE(R2, base_hh1 + 4096, 8);         // g2'

        // ---- u = sigmoid(gpre + b_g) ----
#pragma unroll
        for (int mt = 0; mt < 4; ++mt)
#pragma unroll
            for (int n2 = 0; n2 < 2; ++n2)
#pragma unroll
                for (int r = 0; r < 4; ++r)
                    u_reg[mt][n2][r] = fast_sigmoid(accg[mt][n2][r] + biasg_r[n2]);

        // ---- output projection: staged to LDS, dumped at kernel end ----
        float s1 = 0.f, s2 = 0.f;
#pragma unroll
        for (int c = 0; c < 4; ++c) {
            int kb = oseg * 64 + c * 16;
            bf16x8 hv1 = lds_ld8(lh1 + lds_addr(orow, kb));
            bf16x8 hv2 = lds_ld8(lh2 + lds_addr(orow, kb));
            const float* w1p = wo1 + oseg * 32 + c * 8;
            const float* w2p = wo2 + oseg * 32 + c * 8;
            float4 w10 = *(const float4*)w1p, w11 = *(const float4*)(w1p + 4);
            float4 w20 = *(const float4*)w2p, w21 = *(const float4*)(w2p + 4);
            s1 += (float)hv1[0] * w10.x + (float)hv1[1] * w10.y + (float)hv1[2] * w10.z + (float)hv1[3] * w10.w;
            s1 += (float)hv1[4] * w11.x + (float)hv1[5] * w11.y + (float)hv1[6] * w11.z + (float)hv1[7] * w11.w;
            s2 += (float)hv2[0] * w20.x + (float)hv2[1] * w20.y + (float)hv2[2] * w20.z + (float)hv2[3] * w20.w;
            s2 += (float)hv2[4] * w21.x + (float)hv2[5] * w21.y + (float)hv2[6] * w21.z + (float)hv2[7] * w21.w;
        }
        s1 += __shfl_xor(s1, 1, 8); s1 += __shfl_xor(s1, 2, 8); s1 += __shfl_xor(s1, 4, 8);
        s2 += __shfl_xor(s2, 1, 8); s2 += __shfl_xor(s2, 2, 8); s2 += __shfl_xor(s2, 4, 8);
        if (oseg == 0)
            lout[orow * TSTEPS + t] = fast_tanh(s1 + bo1) + fast_tanh(s2 + bo2);

        // ---- soft-barrier WAIT: phase-align the 32-block group per step ----
        // Perf-only (no data crosses it); bounded spin -> never deadlocks.
        if (tid == 0) {
            unsigned target = 32u * (unsigned)(t + 1);
            int guard = 0;
            while (__hip_atomic_load(gc, __ATOMIC_RELAXED, __HIP_MEMORY_SCOPE_AGENT) < target
                   && guard < 1500) {
                ++guard;
                __builtin_amdgcn_s_sleep(2);
            }
        }
        BAR();  // rest of the block waits for thread 0
    }

    // ---- epilogue: dump staged outputs, fully coalesced ----
    {
        const float* lp = lout + tid * 8;
        f32x4 o0 = {lp[0], lp[1], lp[2], lp[3]};
        f32x4 o1 = {lp[4], lp[5], lp[6], lp[7]};
        float* op = out + (size_t)b0 * TSTEPS + tid * 8;
        *(f32x4*)op = o0;
        *(f32x4*)(op + 4) = o1;
    }
}

extern "C" void kernel_launch(void* const* d_in, const int* in_sizes, int n_in,
                              void* d_out, int out_size, void* d_ws, size_t ws_size,
                              hipStream_t stream) {
    const float* x = (const float*)d_in[0];
    const float* W_ih1 = (const float*)d_in[1];
    const float* b_ih1 = (const float*)d_in[2];
    const float* W_hh1 = (const float*)d_in[3];
    const float* b_hh1 = (const float*)d_in[4];
    const float* W_ih2 = (const float*)d_in[5];
    const float* b_ih2 = (const float*)d_in[6];
    const float* W_hh2 = (const float*)d_in[7];
    const float* b_hh2 = (const float*)d_in[8];
    const float* W_o1 = (const float*)d_in[9];
    const float* b_o1 = (const float*)d_in[10];
    const float* W_o2 = (const float*)d_in[11];
    const float* b_o2 = (const float*)d_in[12];
    const float* W_g = (const float*)d_in[13];
    const float* b_g = (const float*)d_in[14];

    char* ws = (char*)d_ws;
    bf16_t* pw_ih1 = (bf16_t*)(ws + 0);        // 32768 B
    bf16_t* pw_hh1 = (bf16_t*)(ws + 32768);    // 131072 B
    bf16_t* pw_2a = (bf16_t*)(ws + 163840);    // 262144 B
    bf16_t* pw_2b = (bf16_t*)(ws + 425984);    // 131072 B
    bf16_t* pw_3 = (bf16_t*)(ws + 557056);     // 131072 B
    float* bias1 = (float*)(ws + 688128);
    float* bias2a = (float*)(ws + 689152);
    float* biasg = (float*)(ws + 690176);
    unsigned* gsync = (unsigned*)(ws + 692224);  // 8 counters, 128B apart

    pack_w<<<32 * 2, 256, 0, stream>>>(W_ih1, W_ih1, 64, 64, 64, 0, 0, 2, pw_ih1);
    pack_w<<<32 * 8, 256, 0, stream>>>(W_hh1, W_hh1, 256, 256, 256, 0, 0, 8, pw_hh1);
    pack_w<<<32 * 16, 256, 0, stream>>>(W_ih2, W_hh2, 256, 256, 256, 0, 0, 16, pw_2a);
    pack_w<<<32 * 8, 256, 0, stream>>>(W_g, W_g, 256, 512, 512, 0, 0, 8, pw_2b);
    pack_w<<<32 * 8, 256, 0, stream>>>(W_g, W_g, 256, 512, 512, 256, 0, 8, pw_3);
    pack_bias<<<1, 256, 0, stream>>>(b_ih1, b_hh1, b_ih2, b_hh2, b_g, bias1, bias2a, biasg);
    hipMemsetAsync(gsync, 0, 1024, stream);  // reset soft-barrier counters each call

    rnn_main<<<NBLK, 512, 0, stream>>>(x, pw_ih1, pw_hh1, pw_2a, pw_2b, pw_3,
                                       bias1, bias2a, biasg, W_o1, b_o1, W_o2, b_o2,
                                       gsync, (float*)d_out);
}